// Round 2
// baseline (725.563 us; speedup 1.0000x reference)
//
#include <hip/hip_runtime.h>

#define BB 256
#define TT 512
#define II 64
#define DD 512
#define OO 128
#define LN_EPS 1e-5f
#define XS_STRIDE 68   // 64 + 4 pad: rows 16B-aligned; inner reads are
                       // wave-uniform in i so any aligned stride is conflict-free

__device__ __forceinline__ float fast_tanh(float x) {
    // tanh(x) = 1 - 2/(exp(2x)+1); exact saturation at +/-inf
    float e = __expf(2.0f * x);
    return 1.0f - 2.0f / (e + 1.0f);
}

// ---------------------------------------------------------------------------
// Kernel 1: E[b][tau][d] = tanh(X[b, t0+tau, :] . W_in[d, :] + b_in[d])
// 64n x 64d tile per 256-thread block; 4x4 outputs/thread; operands in LDS
// transposed [i][n]. (byte-identical to the verified round-0 kernel)
// ---------------------------------------------------------------------------
__global__ __launch_bounds__(256, 4)
void embed_kernel(const float* __restrict__ x,
                  const float* __restrict__ W_in,
                  const float* __restrict__ b_in,
                  float* __restrict__ E,
                  int t0, int CT)
{
    __shared__ float xs[II][XS_STRIDE];  // [i][n]
    __shared__ float ws[II][XS_STRIDE];  // [i][d]

    const int tiles_per_b = CT >> 6;
    const int bx   = blockIdx.x;
    const int b    = bx / tiles_per_b;
    const int tau0 = (bx - b * tiles_per_b) << 6;   // chunk-local time base
    const int d0   = blockIdx.y << 6;
    const int tid  = threadIdx.x;

    // stage both 64x64 tiles (coalesced float4 global reads, transposed LDS writes)
    {
        const int r0 = tid >> 4;       // 0..15
        const int c4 = tid & 15;       // float4 column
        #pragma unroll
        for (int rr = 0; rr < 4; ++rr) {
            const int row = r0 + (rr << 4);   // 0..63
            const float4 xv = *(const float4*)(x + ((size_t)(b * TT + t0 + tau0 + row)) * II + c4 * 4);
            const float4 wv = *(const float4*)(W_in + ((size_t)(d0 + row)) * II + c4 * 4);
            xs[c4 * 4 + 0][row] = xv.x; xs[c4 * 4 + 1][row] = xv.y;
            xs[c4 * 4 + 2][row] = xv.z; xs[c4 * 4 + 3][row] = xv.w;
            ws[c4 * 4 + 0][row] = wv.x; ws[c4 * 4 + 1][row] = wv.y;
            ws[c4 * 4 + 2][row] = wv.z; ws[c4 * 4 + 3][row] = wv.w;
        }
    }
    __syncthreads();

    const int tn = tid & 15;   // n-group: rows tn*4..tn*4+3
    const int td = tid >> 4;   // d-group: cols td*4..td*4+3

    float acc[4][4];
    #pragma unroll
    for (int j = 0; j < 4; ++j)
        #pragma unroll
        for (int k = 0; k < 4; ++k) acc[j][k] = 0.0f;

    #pragma unroll 8
    for (int i = 0; i < II; ++i) {
        const float4 xv = *(const float4*)&xs[i][tn * 4];  // 16B-aligned, bcast x4
        const float4 wv = *(const float4*)&ws[i][td * 4];  // 16B-aligned, bcast x16
        acc[0][0] = fmaf(xv.x, wv.x, acc[0][0]);
        acc[0][1] = fmaf(xv.x, wv.y, acc[0][1]);
        acc[0][2] = fmaf(xv.x, wv.z, acc[0][2]);
        acc[0][3] = fmaf(xv.x, wv.w, acc[0][3]);
        acc[1][0] = fmaf(xv.y, wv.x, acc[1][0]);
        acc[1][1] = fmaf(xv.y, wv.y, acc[1][1]);
        acc[1][2] = fmaf(xv.y, wv.z, acc[1][2]);
        acc[1][3] = fmaf(xv.y, wv.w, acc[1][3]);
        acc[2][0] = fmaf(xv.z, wv.x, acc[2][0]);
        acc[2][1] = fmaf(xv.z, wv.y, acc[2][1]);
        acc[2][2] = fmaf(xv.z, wv.z, acc[2][2]);
        acc[2][3] = fmaf(xv.z, wv.w, acc[2][3]);
        acc[3][0] = fmaf(xv.w, wv.x, acc[3][0]);
        acc[3][1] = fmaf(xv.w, wv.y, acc[3][1]);
        acc[3][2] = fmaf(xv.w, wv.z, acc[3][2]);
        acc[3][3] = fmaf(xv.w, wv.w, acc[3][3]);
    }

    const int dg = d0 + td * 4;
    const float4 bv = *(const float4*)(b_in + dg);
    #pragma unroll
    for (int j = 0; j < 4; ++j) {
        const int n = tau0 + tn * 4 + j;   // chunk-local time index
        float4 ev;
        ev.x = fast_tanh(acc[j][0] + bv.x);
        ev.y = fast_tanh(acc[j][1] + bv.y);
        ev.z = fast_tanh(acc[j][2] + bv.z);
        ev.w = fast_tanh(acc[j][3] + bv.w);
        *(float4*)(E + ((size_t)(b * CT + n)) * DD + dg) = ev;
    }
}

// ---------------------------------------------------------------------------
// Kernel 2: per-row recurrence + LN, ONE WAVE PER BATCH ROW.
// Lane l owns d = l*8 .. l*8+7 (two float4s). LN reduction = 6-step in-wave
// __shfl_xor butterfly: no __syncthreads, no LDS (removes the ~2900cy/step
// block-barrier chain of the 512-thread version).
// CONSERVATIVE transcription of the proven kernel: named float4 registers
// only (no arrays, no ring indexing), the proven 2-ahead e0/e1/e2 prefetch
// rotation, `#pragma unroll 1`, and identical per-step expression forms.
// ---------------------------------------------------------------------------
__global__ __launch_bounds__(64, 1)
void recur_kernel(const float* __restrict__ E,
                  const float* __restrict__ gamma,
                  const float* __restrict__ beta,
                  const float* __restrict__ W_out,
                  const float* __restrict__ b_out,
                  const float* __restrict__ cs,
                  float* __restrict__ s_state,
                  float* __restrict__ h_state,
                  float* __restrict__ out,
                  int CT, int is_first, int is_last)
{
    const int b     = blockIdx.x;
    const int lane  = threadIdx.x;        // 0..63
    const int dbase = lane << 3;          // lane*8

    const float4 ga = *(const float4*)(gamma + dbase);
    const float4 gb = *(const float4*)(gamma + dbase + 4);
    const float4 za = *(const float4*)(beta  + dbase);
    const float4 zb = *(const float4*)(beta  + dbase + 4);

    const float scale = 1.0f / (1.0f + __expf(-cs[0]));

    float4 spa, spb, hpa, hpb;           // s_prev, h_prev
    if (is_first) {
        spa.x = spa.y = spa.z = spa.w = 0.0f;
        spb = spa; hpa = spa; hpb = spa;
    } else {
        spa = *(const float4*)(s_state + (size_t)b * DD + dbase);
        spb = *(const float4*)(s_state + (size_t)b * DD + dbase + 4);
        hpa = *(const float4*)(h_state + (size_t)b * DD + dbase);
        hpb = *(const float4*)(h_state + (size_t)b * DD + dbase + 4);
    }

    const float* Eb = E + (size_t)b * CT * DD + dbase;

    // proven 2-ahead rotation: e0 = row tau, e1 = row tau+1 (CT >= 64 always)
    float4 e0a = *(const float4*)(Eb);
    float4 e0b = *(const float4*)(Eb + 4);
    float4 e1a = *(const float4*)(Eb + DD);
    float4 e1b = *(const float4*)(Eb + DD + 4);

    #pragma unroll 1
    for (int tau = 0; tau < CT; ++tau) {
        const int tpre = (tau + 2 < CT) ? tau + 2 : CT - 1;
        const float4 e2a = *(const float4*)(Eb + (size_t)tpre * DD);      // prefetch
        const float4 e2b = *(const float4*)(Eb + (size_t)tpre * DD + 4);

        // s = tanh(e + scale*s_prev + h_prev)  — same expression form as the
        // verified kernel (compiler chooses contraction identically)
        float4 sa, sb;
        sa.x = fast_tanh(e0a.x + scale * spa.x + hpa.x);
        sa.y = fast_tanh(e0a.y + scale * spa.y + hpa.y);
        sa.z = fast_tanh(e0a.z + scale * spa.z + hpa.z);
        sa.w = fast_tanh(e0a.w + scale * spa.w + hpa.w);
        sb.x = fast_tanh(e0b.x + scale * spb.x + hpb.x);
        sb.y = fast_tanh(e0b.y + scale * spb.y + hpb.y);
        sb.z = fast_tanh(e0b.z + scale * spb.z + hpb.z);
        sb.w = fast_tanh(e0b.w + scale * spb.w + hpb.w);

        // balanced local trees, then 6-step wave butterfly (all lanes get totals)
        float r0 = ((sa.x + sa.y) + (sa.z + sa.w)) + ((sb.x + sb.y) + (sb.z + sb.w));
        float r1 = ((sa.x * sa.x + sa.y * sa.y) + (sa.z * sa.z + sa.w * sa.w))
                 + ((sb.x * sb.x + sb.y * sb.y) + (sb.z * sb.z + sb.w * sb.w));
        #pragma unroll
        for (int m = 32; m >= 1; m >>= 1) {
            r0 += __shfl_xor(r0, m, 64);
            r1 += __shfl_xor(r1, m, 64);
        }

        const float mu   = r0 * (1.0f / DD);
        const float var  = r1 * (1.0f / DD) - mu * mu;
        const float rstd = rsqrtf(var + LN_EPS);

        hpa.x = (sa.x - mu) * rstd * ga.x + za.x;
        hpa.y = (sa.y - mu) * rstd * ga.y + za.y;
        hpa.z = (sa.z - mu) * rstd * ga.z + za.z;
        hpa.w = (sa.w - mu) * rstd * ga.w + za.w;
        hpb.x = (sb.x - mu) * rstd * gb.x + zb.x;
        hpb.y = (sb.y - mu) * rstd * gb.y + zb.y;
        hpb.z = (sb.z - mu) * rstd * gb.z + zb.z;
        hpb.w = (sb.w - mu) * rstd * gb.w + zb.w;

        spa = sa; spb = sb;
        e0a = e1a; e0b = e1b;
        e1a = e2a; e1b = e2b;
    }

    if (!is_last) {
        *(float4*)(s_state + (size_t)b * DD + dbase)     = spa;
        *(float4*)(s_state + (size_t)b * DD + dbase + 4) = spb;
        *(float4*)(h_state + (size_t)b * DD + dbase)     = hpa;
        *(float4*)(h_state + (size_t)b * DD + dbase + 4) = hpb;
    } else {
        // logits[b, o] = h . W_out[o, :] + b_out[o]; h lives in hpa/hpb per lane.
        for (int o = 0; o < OO; ++o) {
            const float* wo = W_out + (size_t)o * DD + dbase;
            const float4 wa = *(const float4*)(wo);
            const float4 wb = *(const float4*)(wo + 4);
            float p = wa.x * hpa.x + wa.y * hpa.y + wa.z * hpa.z + wa.w * hpa.w
                    + wb.x * hpb.x + wb.y * hpb.y + wb.z * hpb.z + wb.w * hpb.w;
            #pragma unroll
            for (int m = 32; m >= 1; m >>= 1) p += __shfl_xor(p, m, 64);
            if (lane == 0) out[(size_t)b * OO + o] = p + b_out[o];
        }
    }
}

extern "C" void kernel_launch(void* const* d_in, const int* in_sizes, int n_in,
                              void* d_out, int out_size, void* d_ws, size_t ws_size,
                              hipStream_t stream) {
    const float* x      = (const float*)d_in[0];
    const float* W_in   = (const float*)d_in[1];
    const float* b_in   = (const float*)d_in[2];
    const float* gamma  = (const float*)d_in[3];
    const float* beta   = (const float*)d_in[4];
    const float* W_out  = (const float*)d_in[5];
    const float* b_out  = (const float*)d_in[6];
    const float* cs     = (const float*)d_in[7];
    float* out = (float*)d_out;

    // Workspace: [ E_chunk (BB*CT*DD fp32) | s_state (BB*DD) | h_state (BB*DD) ]
    // Pick the largest chunk CT in {512,256,128,64} that fits ws_size.
    const size_t state_bytes = (size_t)BB * DD * sizeof(float);
    int CT = TT;
    while (CT > 64 &&
           (size_t)BB * CT * DD * sizeof(float) + 2 * state_bytes > ws_size) {
        CT >>= 1;
    }
    float* E       = (float*)d_ws;
    float* s_state = (float*)((char*)d_ws + (size_t)BB * CT * DD * sizeof(float));
    float* h_state = s_state + (size_t)BB * DD;

    const int nchunks = TT / CT;
    for (int c = 0; c < nchunks; ++c) {
        dim3 g1(BB * (CT >> 6), DD >> 6);
        embed_kernel<<<g1, 256, 0, stream>>>(x, W_in, b_in, E, c * CT, CT);
        recur_kernel<<<BB, 64, 0, stream>>>(E, gamma, beta, W_out, b_out, cs,
                                            s_state, h_state, out, CT,
                                            (c == 0) ? 1 : 0,
                                            (c == nchunks - 1) ? 1 : 0);
    }
}

// Round 14
// 472.885 us; speedup vs baseline: 1.5343x; 1.5343x over previous
//
#include <hip/hip_runtime.h>

#define BB 256
#define TT 512
#define II 64
#define DD 512
#define OO 128
#define LN_EPS 1e-5f
#define XS_STRIDE 68    // 64 + 4 pad (proven): rows 16B-aligned; inner reads
                        // are wave-uniform in i so any aligned stride works
#define WS_STRIDE 132   // 128 + 4 pad, same property for the 128-wide d tile

__device__ __forceinline__ float fast_tanh(float x) {
    // tanh(x) = 1 - 2/(exp(2x)+1); exact saturation at +/-inf
    float e = __expf(2.0f * x);
    return 1.0f - 2.0f / (e + 1.0f);
}

// ---------------------------------------------------------------------------
// Kernel 1: E[b][tau][d] = tanh(X[b, t0+tau, :] . W_in[d, :] + b_in[d])
// vs round 0: d-tile widened 64 -> 128 (4x8 outputs/thread, 3 ds_read_b128
// per 32 FMA instead of 2 per 16; half the blocks). Each output element still
// accumulates i = 0..63 SEQUENTIALLY with the same fmaf chain, then +b, tanh:
// E is BIT-IDENTICAL to the verified kernel — only indexing changed.
// LDS: 64*68*4 + 64*132*4 = 51.2 KB (< 64 KB static limit, 3 blocks/CU).
// ---------------------------------------------------------------------------
__global__ __launch_bounds__(256, 2)
void embed_kernel(const float* __restrict__ x,
                  const float* __restrict__ W_in,
                  const float* __restrict__ b_in,
                  float* __restrict__ E,
                  int t0, int CT)
{
    __shared__ float xs[II][XS_STRIDE];  // [i][n]  64 x 64 tile
    __shared__ float ws[II][WS_STRIDE];  // [i][d]  64 x 128 tile

    const int tiles_per_b = CT >> 6;               // tau tiles of 64
    const int bx   = blockIdx.x;
    const int b    = bx / tiles_per_b;
    const int tau0 = (bx - b * tiles_per_b) << 6;  // chunk-local time base
    const int d0   = blockIdx.y << 7;              // 128-wide d tile
    const int tid  = threadIdx.x;

    // stage: x 64x64 (rows 0..63), W 128x64 (rows 0..127), transposed to LDS
    {
        const int r0 = tid >> 4;       // 0..15
        const int c4 = tid & 15;       // float4 column along i
        #pragma unroll
        for (int rr = 0; rr < 8; ++rr) {
            const int row = r0 + (rr << 4);   // 0..127
            const float4 wv = *(const float4*)(W_in + ((size_t)(d0 + row)) * II + c4 * 4);
            ws[c4 * 4 + 0][row] = wv.x; ws[c4 * 4 + 1][row] = wv.y;
            ws[c4 * 4 + 2][row] = wv.z; ws[c4 * 4 + 3][row] = wv.w;
            if (rr < 4) {                      // x rows 0..63 only
                const float4 xv = *(const float4*)(x + ((size_t)(b * TT + t0 + tau0 + row)) * II + c4 * 4);
                xs[c4 * 4 + 0][row] = xv.x; xs[c4 * 4 + 1][row] = xv.y;
                xs[c4 * 4 + 2][row] = xv.z; xs[c4 * 4 + 3][row] = xv.w;
            }
        }
    }
    __syncthreads();

    const int tn = tid & 15;   // n-group: rows tn*4..tn*4+3   (16 x 4 = 64)
    const int td = tid >> 4;   // d-group: cols td*8..td*8+7   (16 x 8 = 128)

    float acc[4][8];
    #pragma unroll
    for (int j = 0; j < 4; ++j)
        #pragma unroll
        for (int k = 0; k < 8; ++k) acc[j][k] = 0.0f;

    #pragma unroll 4
    for (int i = 0; i < II; ++i) {
        const float4 xv = *(const float4*)&xs[i][tn * 4];      // bcast x4 lanes
        const float4 wa = *(const float4*)&ws[i][td * 8];      // bcast x16 lanes
        const float4 wb = *(const float4*)&ws[i][td * 8 + 4];
        #pragma unroll
        for (int j = 0; j < 4; ++j) {
            const float xj = (j == 0) ? xv.x : (j == 1) ? xv.y : (j == 2) ? xv.z : xv.w;
            acc[j][0] = fmaf(xj, wa.x, acc[j][0]);
            acc[j][1] = fmaf(xj, wa.y, acc[j][1]);
            acc[j][2] = fmaf(xj, wa.z, acc[j][2]);
            acc[j][3] = fmaf(xj, wa.w, acc[j][3]);
            acc[j][4] = fmaf(xj, wb.x, acc[j][4]);
            acc[j][5] = fmaf(xj, wb.y, acc[j][5]);
            acc[j][6] = fmaf(xj, wb.z, acc[j][6]);
            acc[j][7] = fmaf(xj, wb.w, acc[j][7]);
        }
    }

    const int dg = d0 + td * 8;
    const float4 bv0 = *(const float4*)(b_in + dg);
    const float4 bv1 = *(const float4*)(b_in + dg + 4);
    #pragma unroll
    for (int j = 0; j < 4; ++j) {
        const int n = tau0 + tn * 4 + j;   // chunk-local time index
        float4 e0, e1;
        e0.x = fast_tanh(acc[j][0] + bv0.x);
        e0.y = fast_tanh(acc[j][1] + bv0.y);
        e0.z = fast_tanh(acc[j][2] + bv0.z);
        e0.w = fast_tanh(acc[j][3] + bv0.w);
        e1.x = fast_tanh(acc[j][4] + bv1.x);
        e1.y = fast_tanh(acc[j][5] + bv1.y);
        e1.z = fast_tanh(acc[j][6] + bv1.z);
        e1.w = fast_tanh(acc[j][7] + bv1.w);
        float* dst = E + ((size_t)(b * CT + n)) * DD + dg;
        *(float4*)(dst)     = e0;
        *(float4*)(dst + 4) = e1;
    }
}

// ---------------------------------------------------------------------------
// Kernel 2: per-row recurrence + LN. 4 WAVES (256 threads), 2 d/thread
// (float2). Same proven __shfl_xor butterfly (the ONLY reduce primitive that
// has ever passed on this problem — both DPP formulations failed on HW);
// per-element expression text identical to the verified kernel. Changes vs
// round 0: pair pre-sum before the butterfly, 4-partial exchange instead of
// 8 (cheaper barrier: 4 waves, 1/SIMD), combine read as 2x float4.
// ---------------------------------------------------------------------------
__global__ __launch_bounds__(256)
void recur_kernel(const float* __restrict__ E,
                  const float* __restrict__ gamma,
                  const float* __restrict__ beta,
                  const float* __restrict__ W_out,
                  const float* __restrict__ b_out,
                  const float* __restrict__ cs,
                  float* __restrict__ s_state,
                  float* __restrict__ h_state,
                  float* __restrict__ out,
                  int CT, int is_first, int is_last)
{
    const int b    = blockIdx.x;
    const int tid  = threadIdx.x;      // 0..255
    const int wave = tid >> 6;         // 0..3
    const int lane = tid & 63;
    const int d2   = tid << 1;         // this thread's d base (2 elements)

    __shared__ __align__(16) float red[2][4][2];
    __shared__ float h_lds[DD];

    const float2 g  = *(const float2*)(gamma + d2);
    const float2 bt = *(const float2*)(beta  + d2);
    const float scale = 1.0f / (1.0f + __expf(-cs[0]));

    float2 sp, hp;
    if (is_first) { sp.x = sp.y = 0.0f; hp = sp; }
    else {
        sp = *(const float2*)(s_state + (size_t)b * DD + d2);
        hp = *(const float2*)(h_state + (size_t)b * DD + d2);
    }

    const float* Eb = E + (size_t)b * CT * DD;
    float2 e0 = *(const float2*)(Eb + d2);
    float2 e1 = *(const float2*)(Eb + DD + d2);   // CT >= 64 always

    #pragma unroll 1
    for (int tau = 0; tau < CT; ++tau) {
        const int tpre = (tau + 2 < CT) ? tau + 2 : CT - 1;
        const float2 e2 = *(const float2*)(Eb + (size_t)tpre * DD + d2);  // 2 ahead

        float2 s;
        s.x = fast_tanh(e0.x + scale * sp.x + hp.x);
        s.y = fast_tanh(e0.y + scale * sp.y + hp.y);

        // pair pre-sum, then the PROVEN 6-step shfl_xor butterfly
        float r0 = s.x + s.y;
        float r1 = s.x * s.x + s.y * s.y;
        #pragma unroll
        for (int m = 32; m >= 1; m >>= 1) {
            r0 += __shfl_xor(r0, m, 64);
            r1 += __shfl_xor(r1, m, 64);
        }

        const int p = tau & 1;
        if (lane == 0) { red[p][wave][0] = r0; red[p][wave][1] = r1; }
        __syncthreads();

        const float4 ra = *(const float4*)&red[p][0][0];   // waves 0,1
        const float4 rb = *(const float4*)&red[p][2][0];   // waves 2,3
        const float sum   = (ra.x + ra.z) + (rb.x + rb.z);
        const float sumsq = (ra.y + ra.w) + (rb.y + rb.w);

        const float mu   = sum * (1.0f / DD);
        const float var  = sumsq * (1.0f / DD) - mu * mu;
        const float rstd = rsqrtf(var + LN_EPS);

        hp.x = (s.x - mu) * rstd * g.x + bt.x;
        hp.y = (s.y - mu) * rstd * g.y + bt.y;
        sp = s;
        e0 = e1;
        e1 = e2;
    }

    if (!is_last) {
        *(float2*)(s_state + (size_t)b * DD + d2) = sp;
        *(float2*)(h_state + (size_t)b * DD + d2) = hp;
    } else {
        // logits[b, o] = h . W_out[o, :] + b_out[o]  (proven epilogue pattern;
        // 4 waves x 32 outputs instead of 8 x 16)
        h_lds[d2]     = hp.x;
        h_lds[d2 + 1] = hp.y;
        __syncthreads();

        const int dbase = lane * 8;
        float hreg[8];
        #pragma unroll
        for (int k = 0; k < 8; ++k) hreg[k] = h_lds[dbase + k];

        for (int oo = 0; oo < 32; ++oo) {
            const int o = wave * 32 + oo;
            const float* wo = W_out + (size_t)o * DD + dbase;
            float pacc = 0.f;
            #pragma unroll
            for (int k = 0; k < 8; ++k) pacc = fmaf(wo[k], hreg[k], pacc);
            #pragma unroll
            for (int m = 32; m >= 1; m >>= 1) pacc += __shfl_xor(pacc, m, 64);
            if (lane == 0) out[(size_t)b * OO + o] = pacc + b_out[o];
        }
    }
}

extern "C" void kernel_launch(void* const* d_in, const int* in_sizes, int n_in,
                              void* d_out, int out_size, void* d_ws, size_t ws_size,
                              hipStream_t stream) {
    const float* x      = (const float*)d_in[0];
    const float* W_in   = (const float*)d_in[1];
    const float* b_in   = (const float*)d_in[2];
    const float* gamma  = (const float*)d_in[3];
    const float* beta   = (const float*)d_in[4];
    const float* W_out  = (const float*)d_in[5];
    const float* b_out  = (const float*)d_in[6];
    const float* cs     = (const float*)d_in[7];
    float* out = (float*)d_out;

    // Workspace: [ E_chunk (BB*CT*DD fp32) | s_state (BB*DD) | h_state (BB*DD) ]
    // Pick the largest chunk CT in {512,256,128,64} that fits ws_size.
    const size_t state_bytes = (size_t)BB * DD * sizeof(float);
    int CT = TT;
    while (CT > 64 &&
           (size_t)BB * CT * DD * sizeof(float) + 2 * state_bytes > ws_size) {
        CT >>= 1;
    }
    float* E       = (float*)d_ws;
    float* s_state = (float*)((char*)d_ws + (size_t)BB * CT * DD * sizeof(float));
    float* h_state = s_state + (size_t)BB * DD;

    const int nchunks = TT / CT;
    for (int c = 0; c < nchunks; ++c) {
        dim3 g1(BB * (CT >> 6), DD >> 7);   // d tiles of 128
        embed_kernel<<<g1, 256, 0, stream>>>(x, W_in, b_in, E, c * CT, CT);
        recur_kernel<<<BB, 256, 0, stream>>>(E, gamma, beta, W_out, b_out, cs,
                                             s_state, h_state, out, CT,
                                             (c == 0) ? 1 : 0,
                                             (c == nchunks - 1) ? 1 : 0);
    }
}